// Round 5
// baseline (41295.825 us; speedup 1.0000x reference)
//
#include <hip/hip_runtime.h>
#include <hip/hip_bf16.h>

#define DEV __device__ __forceinline__

DEV float4 ld4(const float* p) { return *reinterpret_cast<const float4*>(p); }
DEV float sigmoidf_(float x) { return 1.f / (1.f + expf(-x)); }

DEV void fma8(float (&a)[8], float xv, float4 wa, float4 wb) {
  a[0] = fmaf(xv, wa.x, a[0]); a[1] = fmaf(xv, wa.y, a[1]);
  a[2] = fmaf(xv, wa.z, a[2]); a[3] = fmaf(xv, wa.w, a[3]);
  a[4] = fmaf(xv, wb.x, a[4]); a[5] = fmaf(xv, wb.y, a[5]);
  a[6] = fmaf(xv, wb.z, a[6]); a[7] = fmaf(xv, wb.w, a[7]);
}
DEV void fma4(float (&a)[4], float xv, float4 wa) {
  a[0] = fmaf(xv, wa.x, a[0]); a[1] = fmaf(xv, wa.y, a[1]);
  a[2] = fmaf(xv, wa.z, a[2]); a[3] = fmaf(xv, wa.w, a[3]);
}
DEV float4 wfma4(float4 a, float w, float4 r) {
  a.x = __fadd_rn(a.x, __fmul_rn(w, r.x));
  a.y = __fadd_rn(a.y, __fmul_rn(w, r.y));
  a.z = __fadd_rn(a.z, __fmul_rn(w, r.z));
  a.w = __fadd_rn(a.w, __fmul_rn(w, r.w));
  return a;
}

// ---------------- CSR build (deterministic, stable) ----------------

__global__ void count_kernel(const int* __restrict__ dst, int* __restrict__ cnt, int E) {
  int e = blockIdx.x * blockDim.x + threadIdx.x;
  if (e < E) atomicAdd(&cnt[dst[e]], 1);  // counts order-independent -> deterministic
}

__global__ __launch_bounds__(256) void blockreduce_kernel(const int* __restrict__ cnt,
                                                          int* __restrict__ bsum, int n) {
  int i = blockIdx.x * 256 + threadIdx.x;
  int v = (i < n) ? cnt[i] : 0;
#pragma unroll
  for (int d = 1; d < 64; d <<= 1) v += __shfl_xor(v, d, 64);
  __shared__ int sh[4];
  if ((threadIdx.x & 63) == 0) sh[threadIdx.x >> 6] = v;
  __syncthreads();
  if (threadIdx.x == 0) bsum[blockIdx.x] = sh[0] + sh[1] + sh[2] + sh[3];
}

__global__ __launch_bounds__(256) void scanb_kernel(const int* __restrict__ bsum,
                                                    int* __restrict__ boff, int nb) {
  __shared__ int sh[256];
  int t = threadIdx.x;
  int orig = (t < nb) ? bsum[t] : 0;
  int v = orig;
  sh[t] = v;
  __syncthreads();
  for (int d = 1; d < 256; d <<= 1) {
    int a = (t >= d) ? sh[t - d] : 0;
    __syncthreads();
    v += a;
    sh[t] = v;
    __syncthreads();
  }
  if (t < nb) boff[t] = v - orig;  // exclusive
}

__global__ __launch_bounds__(256) void blockscan_kernel(
    const int* __restrict__ cnt, const int* __restrict__ boff,
    int* __restrict__ off, int* __restrict__ cur, int n, int total) {
  __shared__ int sh[256];
  int b = blockIdx.x, t = threadIdx.x;
  int i = b * 256 + t;
  int orig = (i < n) ? cnt[i] : 0;
  int v = orig;
  sh[t] = v;
  __syncthreads();
  for (int d = 1; d < 256; d <<= 1) {
    int a = (t >= d) ? sh[t - d] : 0;
    __syncthreads();
    v += a;
    sh[t] = v;
    __syncthreads();
  }
  int excl = v - orig + boff[b];
  if (i < n) { off[i] = excl; cur[i] = excl; }
  if (i == n - 1) off[n] = total;
}

__global__ void scatter_kernel(const int* __restrict__ dstI, int* __restrict__ cur,
                               int* __restrict__ eidx, int E) {
  int e = blockIdx.x * blockDim.x + threadIdx.x;
  if (e < E) {
    int p = atomicAdd(&cur[dstI[e]], 1);
    eidx[p] = e;
  }
}

// per-node wave rank-sort by edge index -> deterministic stable order
// (ascending edge index == np.add.at accumulation order)
__global__ __launch_bounds__(256) void sortseg_kernel(
    const int* __restrict__ off, int* __restrict__ eidx,
    const int* __restrict__ srcI, const float* __restrict__ ew,
    int* __restrict__ csrc, float* __restrict__ cw, int n) {
  int node = blockIdx.x * 4 + (threadIdx.x >> 6);
  int lane = threadIdx.x & 63;
  if (node >= n) return;
  int s = off[node], e = off[node + 1];
  int deg = e - s;
  if (deg <= 0) return;
  if (deg <= 64) {
    int v = (lane < deg) ? eidx[s + lane] : 2147483647;
    int rank = 0;
    for (int m = 0; m < 64; ++m) {
      int u = __shfl(v, m, 64);
      rank += (u < v) ? 1 : 0;  // edge indices unique
    }
    if (lane < deg) {
      csrc[s + rank] = srcI[v];
      cw[s + rank]   = ew[v];
    }
  } else if (lane == 0) {
    for (int i = s + 1; i < e; ++i) {
      int key = eidx[i]; int j = i - 1;
      while (j >= s && eidx[j] > key) { eidx[j + 1] = eidx[j]; --j; }
      eidx[j + 1] = key;
    }
    for (int i = s; i < e; ++i) {
      int v = eidx[i];
      csrc[i] = srcI[v];
      cw[i]   = ew[v];
    }
  }
}

// layer-0 x aggregation for all timesteps (graph is time-invariant)
__global__ __launch_bounds__(256) void aggx0_kernel(
    const int* __restrict__ off, const int* __restrict__ csrc, const float* __restrict__ cw,
    const float* __restrict__ x, float* __restrict__ ax, int n) {
  int node = blockIdx.x * 8 + (threadIdx.x >> 5);
  int lane = threadIdx.x & 31;
  if (node >= n || lane >= 24) return;
  float a = 0.f;
  int s = off[node], e = off[node + 1];
  for (int i = s; i < e; ++i)
    a = __fadd_rn(a, __fmul_rn(cw[i], x[(size_t)csrc[i] * 24 + lane]));
  ax[(size_t)node * 24 + lane] = a;
}

// ---------------- fused agg + gates ----------------
// Phase A: 16-lane group per node gathers h (and o1t for L1) into LDS.
//   Strict ascending edge order, __fmul_rn/__fadd_rn -> bit-identical to the
//   standalone agg kernels.
// Phase B: zr = sigmoid([aggx, aggh] @ Wg + bg); z -> zb, r*h -> rhb.
//   Same per-output fmaf K-order as before (h-part then x-part).

template <int LAYER>
__global__ __launch_bounds__(256) void fgates_kernel(
    const int* __restrict__ off, const int* __restrict__ csrc, const float* __restrict__ cw,
    const float* __restrict__ hb,     // h table: gather source + r*h in epilogue
    const float* __restrict__ xsrc,   // L0: aggx0 + 2t (stride 24); L1: o1t table (gather)
    float* __restrict__ aggx1,        // L1: store aggregated x for fcand; L0: unused
    const float* __restrict__ Wg, const float* __restrict__ bg,
    float* __restrict__ zb, float* __restrict__ rhb, int n) {
  __shared__ float sh_h[16][68];
  __shared__ float sh_x[16][68];
  const int tid = threadIdx.x;
  const int nl = tid >> 4;
  const int node = blockIdx.x * 16 + nl;
  const int g4 = (tid & 15) * 4;

  if (node < n) {
    int s = off[node], e = off[node + 1];
    float4 ah = make_float4(0.f, 0.f, 0.f, 0.f);
    if constexpr (LAYER == 0) {
      for (int i = s; i < e; ++i) {
        float w = cw[i];
        int sn = csrc[i];
        ah = wfma4(ah, w, ld4(hb + (size_t)sn * 64 + g4));
      }
    } else {
      float4 ax = make_float4(0.f, 0.f, 0.f, 0.f);
      for (int i = s; i < e; ++i) {
        float w = cw[i];
        int sn = csrc[i];
        size_t ro = (size_t)sn * 64 + g4;
        ax = wfma4(ax, w, ld4(xsrc + ro));
        ah = wfma4(ah, w, ld4(hb + ro));
      }
      *reinterpret_cast<float4*>(&sh_x[nl][g4]) = ax;
      *reinterpret_cast<float4*>(aggx1 + (size_t)node * 64 + g4) = ax;
    }
    *reinterpret_cast<float4*>(&sh_h[nl][g4]) = ah;
  }
  __syncthreads();
  if (node >= n) return;

  constexpr int KX = (LAYER == 0) ? 2 : 64;
  const int j0 = (tid & 15) * 8;
  float a[8];
#pragma unroll
  for (int i = 0; i < 8; ++i) a[i] = 0.f;

  // h part first (K = 64) -- same order as the unfused kernel
  {
    const float* Wh = Wg + KX * 128;
    for (int k = 0; k < 64; k += 4) {
      float4 f = ld4(&sh_h[nl][k]);
#pragma unroll
      for (int kk = 0; kk < 4; ++kk) {
        const float* wr = Wh + (k + kk) * 128 + j0;
        fma8(a, ((const float*)&f)[kk], ld4(wr), ld4(wr + 4));
      }
    }
  }
  // x part
  if constexpr (LAYER == 0) {
    float x0 = xsrc[(size_t)node * 24];
    float x1 = xsrc[(size_t)node * 24 + 1];
#pragma unroll
    for (int k = 0; k < 2; ++k) {
      const float* wr = Wg + k * 128 + j0;
      fma8(a, k ? x1 : x0, ld4(wr), ld4(wr + 4));
    }
  } else {
    for (int k = 0; k < 64; k += 4) {
      float4 f = ld4(&sh_x[nl][k]);
#pragma unroll
      for (int kk = 0; kk < 4; ++kk) {
        const float* wr = Wg + (k + kk) * 128 + j0;
        fma8(a, ((const float*)&f)[kk], ld4(wr), ld4(wr + 4));
      }
    }
  }
#pragma unroll
  for (int i = 0; i < 8; ++i) {
    int j = j0 + i;
    float sg = sigmoidf_(a[i] + bg[j]);
    if (j < 64) {
      zb[(size_t)node * 64 + j] = sg;
    } else {
      int jj = j - 64;
      rhb[(size_t)node * 64 + jj] = __fmul_rn(sg, hb[(size_t)node * 64 + jj]);
    }
  }
}

// ---------------- fused agg + candidate + GRU update ----------------
// Phase A: gather r*h into LDS (bit-identical chain).
// Phase B: cand = tanh([aggx, aggrh] @ Wc + bc); h = z*h + (1-z)*cand.

template <int LAYER>
__global__ __launch_bounds__(256) void fcand_kernel(
    const int* __restrict__ off, const int* __restrict__ csrc, const float* __restrict__ cw,
    const float* __restrict__ rhb,
    const float* __restrict__ xsrc,   // L0: aggx0 + 2t (stride 24); L1: aggx1 (stride 64)
    const float* __restrict__ Wc, const float* __restrict__ bc,
    const float* __restrict__ zb, float* __restrict__ hb,
    float* __restrict__ outp, int ostride, int n) {
  __shared__ float sh_rh[16][68];
  const int tid = threadIdx.x;
  const int nl = tid >> 4;
  const int node = blockIdx.x * 16 + nl;
  const int g4 = (tid & 15) * 4;

  if (node < n) {
    int s = off[node], e = off[node + 1];
    float4 ar = make_float4(0.f, 0.f, 0.f, 0.f);
    for (int i = s; i < e; ++i) {
      float w = cw[i];
      int sn = csrc[i];
      ar = wfma4(ar, w, ld4(rhb + (size_t)sn * 64 + g4));
    }
    *reinterpret_cast<float4*>(&sh_rh[nl][g4]) = ar;
  }
  __syncthreads();
  if (node >= n) return;

  constexpr int KX = (LAYER == 0) ? 2 : 64;
  const int j0 = (tid & 15) * 4;
  float a[4];
#pragma unroll
  for (int i = 0; i < 4; ++i) a[i] = 0.f;

  // h part first (K = 64)
  {
    const float* Wh = Wc + KX * 64;
    for (int k = 0; k < 64; k += 4) {
      float4 f = ld4(&sh_rh[nl][k]);
#pragma unroll
      for (int kk = 0; kk < 4; ++kk)
        fma4(a, ((const float*)&f)[kk], ld4(Wh + (k + kk) * 64 + j0));
    }
  }
  // x part
  if constexpr (LAYER == 0) {
    float x0 = xsrc[(size_t)node * 24];
    float x1 = xsrc[(size_t)node * 24 + 1];
#pragma unroll
    for (int k = 0; k < 2; ++k)
      fma4(a, k ? x1 : x0, ld4(Wc + k * 64 + j0));
  } else {
    const float* gx = xsrc + (size_t)node * 64;
    for (int k = 0; k < 64; k += 4) {
      float4 f = ld4(gx + k);
#pragma unroll
      for (int kk = 0; kk < 4; ++kk)
        fma4(a, ((const float*)&f)[kk], ld4(Wc + (k + kk) * 64 + j0));
    }
  }
#pragma unroll
  for (int i = 0; i < 4; ++i) {
    int j = j0 + i;
    float c = tanhf(a[i] + bc[j]);
    float z = zb[(size_t)node * 64 + j];
    float h = hb[(size_t)node * 64 + j];
    float hn = __fadd_rn(__fmul_rn(z, h), __fmul_rn(1.f - z, c));  // match np rounding
    hb[(size_t)node * 64 + j] = hn;
    outp[(size_t)node * ostride + j] = hn;
  }
}

// ---------------- launch ----------------

extern "C" void kernel_launch(void* const* d_in, const int* in_sizes, int n_in,
                              void* d_out, int out_size, void* d_ws, size_t ws_size,
                              hipStream_t stream) {
  const float* x   = (const float*)d_in[0];
  const float* h0  = (const float*)d_in[1];
  const int*   ei  = (const int*)  d_in[2];
  const float* ew  = (const float*)d_in[3];
  const float* Wg0 = (const float*)d_in[4];
  const float* bg0 = (const float*)d_in[5];
  const float* Wc0 = (const float*)d_in[6];
  const float* bc0 = (const float*)d_in[7];
  const float* Wg1 = (const float*)d_in[8];
  const float* bg1 = (const float*)d_in[9];
  const float* Wc1 = (const float*)d_in[10];
  const float* bc1 = (const float*)d_in[11];

  const int N = in_sizes[0] / 24;  // T*F = 24
  const int E = in_sizes[2] / 2;
  const int NH = N * 64;
  const int NB = (N + 255) / 256;

  float* h1   = (float*)d_out;      // N*64
  float* h2   = h1 + NH;            // N*64
  float* out2 = h2 + NH;            // N*T*64, layout [n][t][j]

  char* w = (char*)d_ws;
  auto alloc = [&](size_t bytes) {
    char* p = w;
    w += (bytes + 255) & ~(size_t)255;
    return p;
  };
  int*   cnt   = (int*)  alloc((size_t)N * 4);
  int*   off   = (int*)  alloc((size_t)(N + 1) * 4);
  int*   cur   = (int*)  alloc((size_t)N * 4);
  int*   csrc  = (int*)  alloc((size_t)E * 4);
  float* cw    = (float*)alloc((size_t)E * 4);
  int*   bsum  = (int*)  alloc(256 * 4);
  int*   boff  = (int*)  alloc(256 * 4);
  float* aggx0 = (float*)alloc((size_t)N * 24 * 4);
  float* aggx1 = (float*)alloc((size_t)NH * 4);
  float* zb    = (float*)alloc((size_t)NH * 4);
  float* rhb   = (float*)alloc((size_t)NH * 4);
  float* o1t   = (float*)alloc((size_t)NH * 4);
  int*   eidx  = (int*)aggx1;  // alias: aggx1 first written inside the t-loop

  const int* srcI = ei;
  const int* dstI = ei + E;

  hipMemcpyAsync(d_out, h0, (size_t)2 * NH * 4, hipMemcpyDeviceToDevice, stream);

  // deterministic & stable CSR: sorted by (dst, original edge index)
  hipMemsetAsync(cnt, 0, (size_t)N * 4, stream);
  count_kernel<<<(E + 255) / 256, 256, 0, stream>>>(dstI, cnt, E);
  blockreduce_kernel<<<NB, 256, 0, stream>>>(cnt, bsum, N);
  scanb_kernel<<<1, 256, 0, stream>>>(bsum, boff, NB);
  blockscan_kernel<<<NB, 256, 0, stream>>>(cnt, boff, off, cur, N, E);
  scatter_kernel<<<(E + 255) / 256, 256, 0, stream>>>(dstI, cur, eidx, E);
  sortseg_kernel<<<(N + 3) / 4, 256, 0, stream>>>(off, eidx, srcI, ew, csrc, cw, N);

  aggx0_kernel<<<(N + 7) / 8, 256, 0, stream>>>(off, csrc, cw, x, aggx0, N);

  const int gf = (N + 15) / 16;  // fused kernels: 16 nodes/block

  for (int t = 0; t < 12; ++t) {
    // ---- layer 0 ----
    fgates_kernel<0><<<gf, 256, 0, stream>>>(off, csrc, cw, h1, aggx0 + 2 * t, nullptr,
                                             Wg0, bg0, zb, rhb, N);
    fcand_kernel<0><<<gf, 256, 0, stream>>>(off, csrc, cw, rhb, aggx0 + 2 * t,
                                            Wc0, bc0, zb, h1, o1t, 64, N);
    // ---- layer 1 ----
    fgates_kernel<1><<<gf, 256, 0, stream>>>(off, csrc, cw, h2, o1t, aggx1,
                                             Wg1, bg1, zb, rhb, N);
    fcand_kernel<1><<<gf, 256, 0, stream>>>(off, csrc, cw, rhb, aggx1,
                                            Wc1, bc1, zb, h2,
                                            out2 + (size_t)t * 64, 12 * 64, N);
  }
}